// Round 6
// baseline (183.451 us; speedup 1.0000x reference)
//
#include <hip/hip_runtime.h>
#include <hip/hip_bf16.h>

#define NSENT 4000
#define LSEQ  128
#define VEC   50
#define WSTR  52      // bf16 word-emb row stride (shorts): 50 real + 2 zero, 104 B (8B-aligned)
#define NVOCAB 50002
#define POS   5
#define EMBD  60      // VEC + 2*POS
#define HIDD  230
#define HSTR  232     // padded channel stride for H
#define NBAG  500
#define NREL  25
#define NTILEP 16     // padded N-tile count (15 real, tile 15 = zeros)
#define KSTEPS 6      // K = 192 (3 taps * 64 e-slots), 6 MFMA K-steps of 32
#define ESTR  72      // LDS row stride in bf16 shorts (144 B)
#define SLOTS 130     // l+1 shift; rows 0/129 are SAME-pad zeros
#define SSTR  (SLOTS * ESTR)   // per-sentence LDS half
#define WBLOCKS 2540  // prep: wbf part = NVOCAB*13 uint2-threads / 256

// e-slot mapping (A and B MUST agree):
//   e 0..49  = wemb dims 0..49      (e50,51 = 0)
//   e 52..55 = p1 dims 0..3
//   e 56..59 = p2 dims 0..3
//   e 60     = p1 dim 4, e61 = 0
//   e 62     = p2 dim 4, e63 = 0
typedef __attribute__((ext_vector_type(8))) short short8;   // 8 bf16 = 4 VGPRs
typedef __attribute__((ext_vector_type(4))) float f32x4;

__device__ __forceinline__ unsigned short f2bf(float f) {
    union { float f; unsigned u; } v; v.f = f;
    unsigned u = v.u + 0x7FFF + ((v.u >> 16) & 1);   // RNE
    return (unsigned short)(u >> 16);
}

// packed f32x2 -> bf16x2 (v_cvt_pk_bf16_f32 on gfx950), low short = first arg
__device__ __forceinline__ unsigned pk(float a, float b) {
    __hip_bfloat162 h = __float22bfloat162_rn(float2{a, b});
    union { __hip_bfloat162 h; unsigned u; } c; c.h = h;
    return c.u;
}

// ---- merged prep: wbf table cvt (blocks < WBLOCKS) + Bfrag build (rest) ----
__global__ __launch_bounds__(256) void prep(const float* __restrict__ conv_w,
                                            const float* __restrict__ wemb,
                                            unsigned short* __restrict__ Bfrag,
                                            unsigned short* __restrict__ wbf) {
    int bid = blockIdx.x;
    if (bid < WBLOCKS) {
        int idx = bid * 256 + threadIdx.x;        // one uint2 (4 shorts) of wbf
        if (idx < NVOCAB * 13) {
            int r = idx / 13, cj = (idx % 13) * 4;
            const float* src = wemb + (size_t)r * VEC + cj;
            float2 a = *(const float2*)src;
            float2 b = (cj < 48) ? *(const float2*)(src + 2) : float2{0.f, 0.f};
            uint2 v; v.x = pk(a.x, a.y); v.y = pk(b.x, b.y);
            *(uint2*)(wbf + (size_t)r * WSTR + cj) = v;
        }
    } else {
        int idx = (bid - WBLOCKS) * 256 + threadIdx.x;
        if (idx >= NTILEP * KSTEPS * 64 * 8) return;
        int j    = idx & 7;
        int lane = (idx >> 3) & 63;
        int t    = idx >> 9;
        int ks   = t % KSTEPS;
        int nt   = t / KSTEPS;
        int c    = nt * 16 + (lane & 15);
        int klin = ks * 32 + (lane >> 4) * 8 + j;
        int tap  = klin >> 6;
        int e    = klin & 63;
        float v  = 0.f;
        if (c < HIDD) {
            int eidx = -1;
            if (e < 50)                 eidx = e;             // wemb dims
            else if (e >= 52 && e < 56) eidx = 50 + (e - 52); // p1[0..3]
            else if (e >= 56 && e < 60) eidx = 55 + (e - 56); // p2[0..3]
            else if (e == 60)           eidx = 54;            // p1[4]
            else if (e == 62)           eidx = 59;            // p2[4]
            if (eidx >= 0) v = conv_w[(c * EMBD + eidx) * 3 + tap];
        }
        Bfrag[idx] = f2bf(v);
    }
}

// ---- standalone prep_b for the fallback path (no wbf region in ws) ----
__global__ __launch_bounds__(256) void prep_b(const float* __restrict__ conv_w,
                                              unsigned short* __restrict__ Bfrag) {
    int idx = blockIdx.x * 256 + threadIdx.x;
    if (idx >= NTILEP * KSTEPS * 64 * 8) return;
    int j    = idx & 7;
    int lane = (idx >> 3) & 63;
    int t    = idx >> 9;
    int ks   = t % KSTEPS;
    int nt   = t / KSTEPS;
    int c    = nt * 16 + (lane & 15);
    int klin = ks * 32 + (lane >> 4) * 8 + j;
    int tap  = klin >> 6;
    int e    = klin & 63;
    float v  = 0.f;
    if (c < HIDD) {
        int eidx = -1;
        if (e < 50)                 eidx = e;
        else if (e >= 52 && e < 56) eidx = 50 + (e - 52);
        else if (e >= 56 && e < 60) eidx = 55 + (e - 56);
        else if (e == 60)           eidx = 54;
        else if (e == 62)           eidx = 59;
        if (eidx >= 0) v = conv_w[(c * EMBD + eidx) * 3 + tap];
    }
    Bfrag[idx] = f2bf(v);
}

// ---- Kernel 2: FUSED bf16-gather + conv1d(k=3,SAME) MFMA + maxpool + relu ----
// R5 structure (77.5-78.7us measured) with ONE change: the mt loop is
// software-pipelined with double-buffered A fragments (A0/A1, statically
// selected under full unroll). Rationale: at 64 VGPR the compiler could not
// hold A for mt+1 while mt's MFMAs drain (B48+A24 > 64), forcing
// read6 -> lgkmcnt(0) -> mfma12 serialization; MfmaUtil 26% ~= MFMA's 31%
// share of the serialized sum. Budget now: B48 + A0 24 + A1 24 + acc 8 +
// maxv 2 + addr ~10 ~= 116 <= 128 cap of __launch_bounds__(512,4); achieved
// occupancy was 3 waves/EU (38%), cap drops 8->4 waves/EU: no loss.
// SPILL TRIPWIRE: if VGPR_Count > 128 or WRITE_SIZE >> 3.6MB, revert.
// Unchanged (proven): B-load at top, idx staging in LDS, gather pattern,
// sentence-sequential outer with #pragma unroll 1, 2 N-tiles/wave.
__global__ __launch_bounds__(512, 4) void encoder(
    const int*   __restrict__ X,  const int* __restrict__ P1, const int* __restrict__ P2,
    const unsigned short* __restrict__ wbf,
    const float* __restrict__ p1emb, const float* __restrict__ p2emb,
    const unsigned short* __restrict__ Bfrag, const float* __restrict__ conv_b,
    float* __restrict__ H)
{
    __shared__ unsigned short embS[2 * SSTR];   // [sent][slot][e] bf16
    __shared__ int xS[2 * LSEQ], p1S[2 * LSEQ], p2S[2 * LSEQ];
    const int b2 = blockIdx.x * 2, tid = threadIdx.x;
    const int lane = tid & 63;
    const int wave = __builtin_amdgcn_readfirstlane(tid >> 6);
    const int nt0  = wave * 2;
    const int m    = lane & 15;
    const int quad = lane >> 4;

    // ---- this wave's B fragments -> registers (48 VGPRs), issued first
    short8 Bw[2][KSTEPS];
    #pragma unroll
    for (int t = 0; t < 2; ++t)
        #pragma unroll
        for (int ks = 0; ks < KSTEPS; ++ks)
            Bw[t][ks] = *(const short8*)(Bfrag + ((size_t)((nt0 + t) * KSTEPS + ks) * 64 + lane) * 8);

    // ---- stage index rows (both sentences contiguous) + zero pad rows
    #pragma unroll
    for (int it = 0; it < 2; ++it) {
        int i = tid + it * 512;
        if (i < 768) {
            int which = i >> 8, l2 = i & 255;
            const int* src = (which == 0) ? X : (which == 1) ? P1 : P2;
            int v = src[(size_t)b2 * LSEQ + l2];
            int* dst = (which == 0) ? xS : (which == 1) ? p1S : p2S;
            dst[l2] = v;
        } else {
            int t = i - 768;     // 128 dword-writes: 2 sent x 2 pad rows x 64 shorts
            if (t < 128) {
                int sent = t >> 6;
                int r = (t & 32) ? (SLOTS - 1) : 0;
                *(unsigned*)(embS + sent * SSTR + r * ESTR + (t & 31) * 2) = 0u;
            }
        }
    }
    __syncthreads();

    // ---- gather both sentences: 16 lanes/token; word lanes = pure uint2 copy
    #pragma unroll
    for (int it = 0; it < (2 * LSEQ * 16) / 512; ++it) {
        int i = tid + it * 512;
        int sent = i >> 11, rem = i & 2047;
        int l = rem >> 4, j = rem & 15;
        int li = sent * LSEQ + l;
        unsigned short* dst = embS + sent * SSTR + (l + 1) * ESTR;
        uint2 v;
        if (j < 13) {                 // shorts 4j..4j+3 of bf16 row (j=12 brings the 2 zeros)
            v = *(const uint2*)(wbf + (size_t)xS[li] * WSTR + j * 4);
        } else if (j == 13) {         // p1[0..3] -> e52..55
            const float* p = p1emb + p1S[li] * POS;
            v.x = pk(p[0], p[1]); v.y = pk(p[2], p[3]);
        } else if (j == 14) {         // p2[0..3] -> e56..59
            const float* p = p2emb + p2S[li] * POS;
            v.x = pk(p[0], p[1]); v.y = pk(p[2], p[3]);
        } else {                      // tails -> e60..63
            float a = p1emb[p1S[li] * POS + 4];
            float b = p2emb[p2S[li] * POS + 4];
            v.x = pk(a, 0.f); v.y = pk(b, 0.f);
        }
        *(uint2*)(dst + (j < 13 ? j * 4 : 52 + (j - 13) * 4)) = v;
    }
    __syncthreads();

    // ---- sentences sequentially; mt loop software-pipelined (A dbuf)
    #pragma unroll 1
    for (int s = 0; s < 2; ++s) {
        const unsigned short* eb = embS + s * SSTR;
        float maxv0 = -1e30f, maxv1 = -1e30f;
        short8 A0[KSTEPS], A1[KSTEPS];

        // prologue: mt = 0 fragments
        #pragma unroll
        for (int ks = 0; ks < KSTEPS; ++ks) {
            int tap = ks >> 1;
            int col = (ks & 1) * 32 + quad * 8;
            A0[ks] = *(const short8*)(eb + (m + tap) * ESTR + col);
        }

        #pragma unroll
        for (int mt = 0; mt < 8; ++mt) {
            const short8* Ac = (mt & 1) ? A1 : A0;   // static after full unroll
            short8*       An = (mt & 1) ? A0 : A1;
            if (mt < 7) {                            // issue mt+1 reads BEFORE mt's MFMAs
                #pragma unroll
                for (int ks = 0; ks < KSTEPS; ++ks) {
                    int tap = ks >> 1;
                    int col = (ks & 1) * 32 + quad * 8;
                    int row = (mt + 1) * 16 + m + tap;
                    An[ks] = *(const short8*)(eb + row * ESTR + col);
                }
            }
            f32x4 acc0 = (f32x4){0.f, 0.f, 0.f, 0.f};
            f32x4 acc1 = (f32x4){0.f, 0.f, 0.f, 0.f};
            #pragma unroll
            for (int ks = 0; ks < KSTEPS; ++ks) {
                acc0 = __builtin_amdgcn_mfma_f32_16x16x32_bf16(Ac[ks], Bw[0][ks], acc0, 0, 0, 0);
                acc1 = __builtin_amdgcn_mfma_f32_16x16x32_bf16(Ac[ks], Bw[1][ks], acc1, 0, 0, 0);
            }
            maxv0 = fmaxf(maxv0, fmaxf(fmaxf(acc0[0], acc0[1]), fmaxf(acc0[2], acc0[3])));
            maxv1 = fmaxf(maxv1, fmaxf(fmaxf(acc1[0], acc1[1]), fmaxf(acc1[2], acc1[3])));
        }

        // reduce quads via xor 16/32 -> bias + relu -> H
        #pragma unroll
        for (int t = 0; t < 2; ++t) {
            float v = t ? maxv1 : maxv0;
            v = fmaxf(v, __shfl_xor(v, 16));
            v = fmaxf(v, __shfl_xor(v, 32));
            int c = (nt0 + t) * 16 + lane;
            if (lane < 16 && c < HIDD)
                H[(size_t)(b2 + s) * HSTR + c] = fmaxf(v + conv_b[c], 0.f);
        }
    }
}

// ---- fallback: the proven round-0 fused encoder with f32 wemb (verbatim) ----
__global__ __launch_bounds__(512, 4) void encoder_f32(
    const int*   __restrict__ X,  const int* __restrict__ P1, const int* __restrict__ P2,
    const float* __restrict__ wemb, const float* __restrict__ p1emb, const float* __restrict__ p2emb,
    const unsigned short* __restrict__ Bfrag, const float* __restrict__ conv_b,
    float* __restrict__ H)
{
    __shared__ unsigned short embS[2 * SSTR];
    __shared__ int xS[2 * LSEQ], p1S[2 * LSEQ], p2S[2 * LSEQ];
    const int b2 = blockIdx.x * 2, tid = threadIdx.x;
    const int lane = tid & 63;
    const int wave = __builtin_amdgcn_readfirstlane(tid >> 6);
    const int nt0  = wave * 2;
    const int m    = lane & 15;
    const int quad = lane >> 4;

    short8 Bw[2][KSTEPS];
    #pragma unroll
    for (int t = 0; t < 2; ++t)
        #pragma unroll
        for (int ks = 0; ks < KSTEPS; ++ks)
            Bw[t][ks] = *(const short8*)(Bfrag + ((size_t)((nt0 + t) * KSTEPS + ks) * 64 + lane) * 8);

    #pragma unroll
    for (int it = 0; it < 2; ++it) {
        int i = tid + it * 512;
        if (i < 768) {
            int which = i >> 8, l2 = i & 255;
            const int* src = (which == 0) ? X : (which == 1) ? P1 : P2;
            int v = src[(size_t)b2 * LSEQ + l2];
            int* dst = (which == 0) ? xS : (which == 1) ? p1S : p2S;
            dst[l2] = v;
        } else {
            int t = i - 768;
            if (t < 128) {
                int sent = t >> 6;
                int r = (t & 32) ? (SLOTS - 1) : 0;
                *(unsigned*)(embS + sent * SSTR + r * ESTR + (t & 31) * 2) = 0u;
            }
        }
    }
    __syncthreads();

    #pragma unroll
    for (int it = 0; it < (2 * LSEQ * 16) / 512; ++it) {
        int i = tid + it * 512;
        int sent = i >> 11, rem = i & 2047;
        int l = rem >> 4, j = rem & 15;
        int li = sent * LSEQ + l;
        unsigned short* dst = embS + sent * SSTR + (l + 1) * ESTR;
        uint2 v;
        if (j < 13) {
            const float* src = wemb + (size_t)xS[li] * VEC + j * 4;
            float2 fa = *(const float2*)(src);
            float a2 = 0.f, a3 = 0.f;
            if (j < 12) { float2 fb = *(const float2*)(src + 2); a2 = fb.x; a3 = fb.y; }
            v.x = pk(fa.x, fa.y); v.y = pk(a2, a3);
        } else if (j == 13) {
            const float* p = p1emb + p1S[li] * POS;
            v.x = pk(p[0], p[1]); v.y = pk(p[2], p[3]);
        } else if (j == 14) {
            const float* p = p2emb + p2S[li] * POS;
            v.x = pk(p[0], p[1]); v.y = pk(p[2], p[3]);
        } else {
            float a = p1emb[p1S[li] * POS + 4];
            float b = p2emb[p2S[li] * POS + 4];
            v.x = pk(a, 0.f); v.y = pk(b, 0.f);
        }
        *(uint2*)(dst + (j < 13 ? j * 4 : 52 + (j - 13) * 4)) = v;
    }
    __syncthreads();

    #pragma unroll 1
    for (int s = 0; s < 2; ++s) {
        const unsigned short* eb = embS + s * SSTR;
        float maxv[2][4];
        #pragma unroll
        for (int t = 0; t < 2; ++t)
            #pragma unroll
            for (int r = 0; r < 4; ++r) maxv[t][r] = -1e30f;

        #pragma unroll
        for (int mt = 0; mt < 8; ++mt) {
            short8 A[KSTEPS];
            #pragma unroll
            for (int ks = 0; ks < KSTEPS; ++ks) {
                int tap = ks >> 1;
                int col = (ks & 1) * 32 + quad * 8;
                int row = mt * 16 + m + tap;
                A[ks] = *(const short8*)(eb + row * ESTR + col);
            }
            f32x4 acc[2];
            #pragma unroll
            for (int t = 0; t < 2; ++t) acc[t] = (f32x4){0.f, 0.f, 0.f, 0.f};
            #pragma unroll
            for (int ks = 0; ks < KSTEPS; ++ks)
                #pragma unroll
                for (int t = 0; t < 2; ++t)
                    acc[t] = __builtin_amdgcn_mfma_f32_16x16x32_bf16(A[ks], Bw[t][ks], acc[t], 0, 0, 0);
            #pragma unroll
            for (int t = 0; t < 2; ++t)
                #pragma unroll
                for (int r = 0; r < 4; ++r)
                    maxv[t][r] = fmaxf(maxv[t][r], acc[t][r]);
        }

        #pragma unroll
        for (int t = 0; t < 2; ++t) {
            float v = fmaxf(fmaxf(maxv[t][0], maxv[t][1]),
                            fmaxf(maxv[t][2], maxv[t][3]));
            v = fmaxf(v, __shfl_xor(v, 16));
            v = fmaxf(v, __shfl_xor(v, 32));
            int c = (nt0 + t) * 16 + lane;
            if (lane < 16 && c < HIDD)
                H[(size_t)(b2 + s) * HSTR + c] = fmaxf(v + conv_b[c], 0.f);
        }
    }
}

// ---- Kernel 3: one wave per bag, zero barriers, all state in registers ----
__global__ __launch_bounds__(64) void attn(
    const float* __restrict__ H, const float* __restrict__ rel_w, const float* __restrict__ rel_b,
    const int* __restrict__ relation, const int* __restrict__ scope,
    float* __restrict__ out)
{
    const int b = blockIdx.x, lane = threadIdx.x;
    const int start = scope[2 * b];
    int ns = scope[2 * b + 1] - start;
    if (ns > 8) ns = 8;
    const int rel = relation[b];

    float q[4], h[8][4];
    #pragma unroll
    for (int k = 0; k < 4; ++k) {
        int c = lane + 64 * k;
        q[k] = (c < HIDD) ? rel_w[rel * HIDD + c] : 0.f;
    }
    #pragma unroll
    for (int s = 0; s < 8; ++s)
        #pragma unroll
        for (int k = 0; k < 4; ++k) {
            int c = lane + 64 * k;
            h[s][k] = (s < ns && c < HIDD) ? H[(size_t)(start + s) * HSTR + c] : 0.f;
        }

    float logit[8];
    #pragma unroll
    for (int s = 0; s < 8; ++s) {
        float t = q[0] * h[s][0] + q[1] * h[s][1] + q[2] * h[s][2] + q[3] * h[s][3];
        #pragma unroll
        for (int off = 32; off > 0; off >>= 1) t += __shfl_xor(t, off);
        logit[s] = t;   // all lanes hold it
    }

    float mx = -1e30f;
    for (int s = 0; s < ns; ++s) mx = fmaxf(mx, logit[s]);
    float a[8], den = 0.f;
    #pragma unroll
    for (int s = 0; s < 8; ++s) { a[s] = (s < ns) ? expf(logit[s] - mx) : 0.f; den += a[s]; }
    float inv = 1.f / den;

    float rep[4];
    #pragma unroll
    for (int k = 0; k < 4; ++k) {
        float r = 0.f;
        #pragma unroll
        for (int s = 0; s < 8; ++s) r += a[s] * h[s][k];
        rep[k] = r * inv;
    }

    // classifier: 25 rows of rel_w, coalesced wave reads (L2-broadcast)
    #pragma unroll 5
    for (int g = 0; g < NREL; ++g) {
        float t = 0.f;
        #pragma unroll
        for (int k = 0; k < 4; ++k) {
            int c = lane + 64 * k;
            t += (c < HIDD) ? rel_w[g * HIDD + c] * rep[k] : 0.f;
        }
        #pragma unroll
        for (int off = 32; off > 0; off >>= 1) t += __shfl_xor(t, off);
        if (lane == 0) out[b * NREL + g] = t + rel_b[g];
    }
}

extern "C" void kernel_launch(void* const* d_in, const int* in_sizes, int n_in,
                              void* d_out, int out_size, void* d_ws, size_t ws_size,
                              hipStream_t stream) {
    const int*   X        = (const int*)d_in[0];
    const int*   P1       = (const int*)d_in[1];
    const int*   P2       = (const int*)d_in[2];
    const int*   scope    = (const int*)d_in[5];
    const int*   relation = (const int*)d_in[6];
    const float* wemb     = (const float*)d_in[7];
    const float* p1emb    = (const float*)d_in[8];
    const float* p2emb    = (const float*)d_in[9];
    const float* conv_w   = (const float*)d_in[10];
    const float* conv_b   = (const float*)d_in[11];
    const float* rel_w    = (const float*)d_in[12];
    const float* rel_b    = (const float*)d_in[13];

    // workspace layout
    char* ws = (char*)d_ws;
    float* H = (float*)ws;                                   // 4000*232*4 = 3,712,000
    const size_t offB = (size_t)NSENT * HSTR * 4;
    unsigned short* Bfrag = (unsigned short*)(ws + offB);    // 16*6*64*8*2 = 98,304
    const size_t offW = offB + (size_t)NTILEP * KSTEPS * 64 * 8 * 2;
    unsigned short* wbf = (unsigned short*)(ws + offW);      // 50002*52*2 = 5,200,208
    const size_t need = offW + (size_t)NVOCAB * WSTR * 2;

    if (ws_size >= need) {
        // merged prep: wbf cvt (2540 blocks) + Bfrag build (192 blocks)
        hipLaunchKernelGGL(prep, dim3(WBLOCKS + 192), dim3(256), 0, stream,
                           conv_w, wemb, Bfrag, wbf);
        hipLaunchKernelGGL(encoder, dim3(NSENT / 2), dim3(512), 0, stream,
                           X, P1, P2, wbf, p1emb, p2emb, Bfrag, conv_b, H);
    } else {
        const int btot = NTILEP * KSTEPS * 64 * 8;
        hipLaunchKernelGGL(prep_b, dim3((btot + 255) / 256), dim3(256), 0, stream,
                           conv_w, Bfrag);
        hipLaunchKernelGGL(encoder_f32, dim3(NSENT / 2), dim3(512), 0, stream,
                           X, P1, P2, wemb, p1emb, p2emb, Bfrag, conv_b, H);
    }
    hipLaunchKernelGGL(attn, dim3(NBAG), dim3(64), 0, stream,
                       H, rel_w, rel_b, relation, scope, (float*)d_out);
}

// Round 7
// 179.983 us; speedup vs baseline: 1.0193x; 1.0193x over previous
//
#include <hip/hip_runtime.h>
#include <hip/hip_bf16.h>

#define NSENT 4000
#define LSEQ  128
#define VEC   50
#define WSTR  52      // bf16 word-emb row stride (shorts): 50 real + 2 zero, 104 B (8B-aligned)
#define NVOCAB 50002
#define POS   5
#define EMBD  60      // VEC + 2*POS
#define HIDD  230
#define HSTR  232     // padded channel stride for H
#define NBAG  500
#define NREL  25
#define NTILEP 16     // padded N-tile count (15 real, tile 15 = zeros)
#define KSTEPS 6      // K = 192 (3 taps * 64 e-slots), 6 MFMA K-steps of 32
#define ESTR  72      // LDS row stride in bf16 shorts (144 B)
#define SLOTS 130     // l+1 shift; rows 0/129 are SAME-pad zeros
#define SSTR  (SLOTS * ESTR)   // per-sentence LDS half
#define WBLOCKS 2540  // prep: wbf part = NVOCAB*13 uint2-threads / 256

// e-slot mapping (A and B MUST agree):
//   e 0..49  = wemb dims 0..49      (e50,51 = 0)
//   e 52..55 = p1 dims 0..3
//   e 56..59 = p2 dims 0..3
//   e 60     = p1 dim 4, e61 = 0
//   e 62     = p2 dim 4, e63 = 0
typedef __attribute__((ext_vector_type(8))) short short8;   // 8 bf16 = 4 VGPRs
typedef __attribute__((ext_vector_type(4))) float f32x4;

__device__ __forceinline__ unsigned short f2bf(float f) {
    union { float f; unsigned u; } v; v.f = f;
    unsigned u = v.u + 0x7FFF + ((v.u >> 16) & 1);   // RNE
    return (unsigned short)(u >> 16);
}

// packed f32x2 -> bf16x2 (v_cvt_pk_bf16_f32 on gfx950), low short = first arg
__device__ __forceinline__ unsigned pk(float a, float b) {
    __hip_bfloat162 h = __float22bfloat162_rn(float2{a, b});
    union { __hip_bfloat162 h; unsigned u; } c; c.h = h;
    return c.u;
}

// ---- merged prep: wbf table cvt (blocks < WBLOCKS) + Bfrag build (rest) ----
__global__ __launch_bounds__(256) void prep(const float* __restrict__ conv_w,
                                            const float* __restrict__ wemb,
                                            unsigned short* __restrict__ Bfrag,
                                            unsigned short* __restrict__ wbf) {
    int bid = blockIdx.x;
    if (bid < WBLOCKS) {
        int idx = bid * 256 + threadIdx.x;        // one uint2 (4 shorts) of wbf
        if (idx < NVOCAB * 13) {
            int r = idx / 13, cj = (idx % 13) * 4;
            const float* src = wemb + (size_t)r * VEC + cj;
            float2 a = *(const float2*)src;
            float2 b = (cj < 48) ? *(const float2*)(src + 2) : float2{0.f, 0.f};
            uint2 v; v.x = pk(a.x, a.y); v.y = pk(b.x, b.y);
            *(uint2*)(wbf + (size_t)r * WSTR + cj) = v;
        }
    } else {
        int idx = (bid - WBLOCKS) * 256 + threadIdx.x;
        if (idx >= NTILEP * KSTEPS * 64 * 8) return;
        int j    = idx & 7;
        int lane = (idx >> 3) & 63;
        int t    = idx >> 9;
        int ks   = t % KSTEPS;
        int nt   = t / KSTEPS;
        int c    = nt * 16 + (lane & 15);
        int klin = ks * 32 + (lane >> 4) * 8 + j;
        int tap  = klin >> 6;
        int e    = klin & 63;
        float v  = 0.f;
        if (c < HIDD) {
            int eidx = -1;
            if (e < 50)                 eidx = e;             // wemb dims
            else if (e >= 52 && e < 56) eidx = 50 + (e - 52); // p1[0..3]
            else if (e >= 56 && e < 60) eidx = 55 + (e - 56); // p2[0..3]
            else if (e == 60)           eidx = 54;            // p1[4]
            else if (e == 62)           eidx = 59;            // p2[4]
            if (eidx >= 0) v = conv_w[(c * EMBD + eidx) * 3 + tap];
        }
        Bfrag[idx] = f2bf(v);
    }
}

// ---- standalone prep_b for the fallback path (no wbf region in ws) ----
__global__ __launch_bounds__(256) void prep_b(const float* __restrict__ conv_w,
                                              unsigned short* __restrict__ Bfrag) {
    int idx = blockIdx.x * 256 + threadIdx.x;
    if (idx >= NTILEP * KSTEPS * 64 * 8) return;
    int j    = idx & 7;
    int lane = (idx >> 3) & 63;
    int t    = idx >> 9;
    int ks   = t % KSTEPS;
    int nt   = t / KSTEPS;
    int c    = nt * 16 + (lane & 15);
    int klin = ks * 32 + (lane >> 4) * 8 + j;
    int tap  = klin >> 6;
    int e    = klin & 63;
    float v  = 0.f;
    if (c < HIDD) {
        int eidx = -1;
        if (e < 50)                 eidx = e;
        else if (e >= 52 && e < 56) eidx = 50 + (e - 52);
        else if (e >= 56 && e < 60) eidx = 55 + (e - 56);
        else if (e == 60)           eidx = 54;
        else if (e == 62)           eidx = 59;
        if (eidx >= 0) v = conv_w[(c * EMBD + eidx) * 3 + tap];
    }
    Bfrag[idx] = f2bf(v);
}

// ---- gather one sentence: 16 lanes/token; word lanes = pure uint2 copy ----
__device__ __forceinline__ void gather_one(
    int s, int tid,
    const int* __restrict__ xS, const int* __restrict__ p1S, const int* __restrict__ p2S,
    const unsigned short* __restrict__ wbf,
    const float* __restrict__ p1emb, const float* __restrict__ p2emb,
    unsigned short* __restrict__ embS)
{
    #pragma unroll
    for (int it = 0; it < (LSEQ * 16) / 512; ++it) {
        int i = tid + it * 512;
        int l = i >> 4, j = i & 15;
        int li = s * LSEQ + l;
        unsigned short* dst = embS + s * SSTR + (l + 1) * ESTR;
        uint2 v;
        if (j < 13) {                 // shorts 4j..4j+3 of bf16 row (j=12 brings the 2 zeros)
            v = *(const uint2*)(wbf + (size_t)xS[li] * WSTR + j * 4);
        } else if (j == 13) {         // p1[0..3] -> e52..55
            const float* p = p1emb + p1S[li] * POS;
            v.x = pk(p[0], p[1]); v.y = pk(p[2], p[3]);
        } else if (j == 14) {         // p2[0..3] -> e56..59
            const float* p = p2emb + p2S[li] * POS;
            v.x = pk(p[0], p[1]); v.y = pk(p[2], p[3]);
        } else {                      // tails -> e60..63
            float a = p1emb[p1S[li] * POS + 4];
            float b = p2emb[p2S[li] * POS + 4];
            v.x = pk(a, 0.f); v.y = pk(b, 0.f);
        }
        *(uint2*)(dst + (j < 13 ? j * 4 : 52 + (j - 13) * 4)) = v;
    }
}

// ---- compute one sentence: the PROVEN R5 inner loop, verbatim ----
__device__ __forceinline__ void compute_one(
    const unsigned short* __restrict__ eb, const short8 Bw[2][KSTEPS],
    int m, int quad, int nt0, int lane, int sent_row,
    const float* __restrict__ conv_b, float* __restrict__ H)
{
    float maxv[2][4];
    #pragma unroll
    for (int t = 0; t < 2; ++t)
        #pragma unroll
        for (int r = 0; r < 4; ++r) maxv[t][r] = -1e30f;

    #pragma unroll
    for (int mt = 0; mt < 8; ++mt) {
        short8 A[KSTEPS];
        #pragma unroll
        for (int ks = 0; ks < KSTEPS; ++ks) {
            int tap = ks >> 1;
            int col = (ks & 1) * 32 + quad * 8;
            int row = mt * 16 + m + tap;        // slot (l+tap), +1 shift folded in
            A[ks] = *(const short8*)(eb + row * ESTR + col);
        }
        f32x4 acc[2];
        #pragma unroll
        for (int t = 0; t < 2; ++t) acc[t] = (f32x4){0.f, 0.f, 0.f, 0.f};
        #pragma unroll
        for (int ks = 0; ks < KSTEPS; ++ks)
            #pragma unroll
            for (int t = 0; t < 2; ++t)
                acc[t] = __builtin_amdgcn_mfma_f32_16x16x32_bf16(A[ks], Bw[t][ks], acc[t], 0, 0, 0);
        #pragma unroll
        for (int t = 0; t < 2; ++t)
            #pragma unroll
            for (int r = 0; r < 4; ++r)
                maxv[t][r] = fmaxf(maxv[t][r], acc[t][r]);
    }

    // reduce rows (4 regs, then quads via xor 16/32) -> bias + relu -> H
    #pragma unroll
    for (int t = 0; t < 2; ++t) {
        float v = fmaxf(fmaxf(maxv[t][0], maxv[t][1]),
                        fmaxf(maxv[t][2], maxv[t][3]));
        v = fmaxf(v, __shfl_xor(v, 16));
        v = fmaxf(v, __shfl_xor(v, 32));
        int c = (nt0 + t) * 16 + lane;
        if (lane < 16 && c < HIDD)
            H[(size_t)sent_row * HSTR + c] = fmaxf(v + conv_b[c], 0.f);
    }
}

// ---- Kernel 2: FUSED bf16-gather + conv1d(k=3,SAME) MFMA + maxpool + relu ----
// R5 code (measured 78.7us) with ONE ORDERING change (no liveness change —
// R3/R6 proved the allocator rejects anything needing >64 VGPR):
//   old: gather(s0+s1); bar; compute(s0); compute(s1)
//   new: gather(s0); bar; gather(s1); compute(s0); bar; compute(s1)
// gather(s1) and compute(s0) share one scheduling region and are fully
// independent (disjoint LDS), so the scheduler can hoist s1's global loads
// under s0's MFMA stream — T14 issue-early by program order, zero registers
// held across phases. Exposed gather latency drops from 2 sentences to 1.
// Unchanged (proven): B-load at top, idx staging in LDS, 2 N-tiles/wave,
// 16-lane/token gather pattern, compute inner loop verbatim.
__global__ __launch_bounds__(512, 4) void encoder(
    const int*   __restrict__ X,  const int* __restrict__ P1, const int* __restrict__ P2,
    const unsigned short* __restrict__ wbf,
    const float* __restrict__ p1emb, const float* __restrict__ p2emb,
    const unsigned short* __restrict__ Bfrag, const float* __restrict__ conv_b,
    float* __restrict__ H)
{
    __shared__ unsigned short embS[2 * SSTR];   // [sent][slot][e] bf16
    __shared__ int xS[2 * LSEQ], p1S[2 * LSEQ], p2S[2 * LSEQ];
    const int b2 = blockIdx.x * 2, tid = threadIdx.x;
    const int lane = tid & 63;
    const int wave = __builtin_amdgcn_readfirstlane(tid >> 6);
    const int nt0  = wave * 2;
    const int m    = lane & 15;
    const int quad = lane >> 4;

    // ---- this wave's B fragments -> registers (48 VGPRs), issued first
    short8 Bw[2][KSTEPS];
    #pragma unroll
    for (int t = 0; t < 2; ++t)
        #pragma unroll
        for (int ks = 0; ks < KSTEPS; ++ks)
            Bw[t][ks] = *(const short8*)(Bfrag + ((size_t)((nt0 + t) * KSTEPS + ks) * 64 + lane) * 8);

    // ---- stage index rows (both sentences contiguous) + zero pad rows
    #pragma unroll
    for (int it = 0; it < 2; ++it) {
        int i = tid + it * 512;
        if (i < 768) {
            int which = i >> 8, l2 = i & 255;
            const int* src = (which == 0) ? X : (which == 1) ? P1 : P2;
            int v = src[(size_t)b2 * LSEQ + l2];
            int* dst = (which == 0) ? xS : (which == 1) ? p1S : p2S;
            dst[l2] = v;
        } else {
            int t = i - 768;     // 128 dword-writes: 2 sent x 2 pad rows x 64 shorts
            if (t < 128) {
                int sent = t >> 6;
                int r = (t & 32) ? (SLOTS - 1) : 0;
                *(unsigned*)(embS + sent * SSTR + r * ESTR + (t & 31) * 2) = 0u;
            }
        }
    }
    __syncthreads();

    // ---- sentence 0 gather, then barrier so compute(s0) can start
    gather_one(0, tid, xS, p1S, p2S, wbf, p1emb, p2emb, embS);
    __syncthreads();

    // ---- sentence 1 gather overlapped with sentence 0 compute
    gather_one(1, tid, xS, p1S, p2S, wbf, p1emb, p2emb, embS);
    compute_one(embS, Bw, m, quad, nt0, lane, b2 + 0, conv_b, H);
    __syncthreads();

    // ---- sentence 1 compute
    compute_one(embS + SSTR, Bw, m, quad, nt0, lane, b2 + 1, conv_b, H);
}

// ---- fallback: the proven round-0 fused encoder with f32 wemb (verbatim) ----
__global__ __launch_bounds__(512, 4) void encoder_f32(
    const int*   __restrict__ X,  const int* __restrict__ P1, const int* __restrict__ P2,
    const float* __restrict__ wemb, const float* __restrict__ p1emb, const float* __restrict__ p2emb,
    const unsigned short* __restrict__ Bfrag, const float* __restrict__ conv_b,
    float* __restrict__ H)
{
    __shared__ unsigned short embS[2 * SSTR];
    __shared__ int xS[2 * LSEQ], p1S[2 * LSEQ], p2S[2 * LSEQ];
    const int b2 = blockIdx.x * 2, tid = threadIdx.x;
    const int lane = tid & 63;
    const int wave = __builtin_amdgcn_readfirstlane(tid >> 6);
    const int nt0  = wave * 2;
    const int m    = lane & 15;
    const int quad = lane >> 4;

    short8 Bw[2][KSTEPS];
    #pragma unroll
    for (int t = 0; t < 2; ++t)
        #pragma unroll
        for (int ks = 0; ks < KSTEPS; ++ks)
            Bw[t][ks] = *(const short8*)(Bfrag + ((size_t)((nt0 + t) * KSTEPS + ks) * 64 + lane) * 8);

    #pragma unroll
    for (int it = 0; it < 2; ++it) {
        int i = tid + it * 512;
        if (i < 768) {
            int which = i >> 8, l2 = i & 255;
            const int* src = (which == 0) ? X : (which == 1) ? P1 : P2;
            int v = src[(size_t)b2 * LSEQ + l2];
            int* dst = (which == 0) ? xS : (which == 1) ? p1S : p2S;
            dst[l2] = v;
        } else {
            int t = i - 768;
            if (t < 128) {
                int sent = t >> 6;
                int r = (t & 32) ? (SLOTS - 1) : 0;
                *(unsigned*)(embS + sent * SSTR + r * ESTR + (t & 31) * 2) = 0u;
            }
        }
    }
    __syncthreads();

    #pragma unroll
    for (int it = 0; it < (2 * LSEQ * 16) / 512; ++it) {
        int i = tid + it * 512;
        int sent = i >> 11, rem = i & 2047;
        int l = rem >> 4, j = rem & 15;
        int li = sent * LSEQ + l;
        unsigned short* dst = embS + sent * SSTR + (l + 1) * ESTR;
        uint2 v;
        if (j < 13) {
            const float* src = wemb + (size_t)xS[li] * VEC + j * 4;
            float2 fa = *(const float2*)(src);
            float a2 = 0.f, a3 = 0.f;
            if (j < 12) { float2 fb = *(const float2*)(src + 2); a2 = fb.x; a3 = fb.y; }
            v.x = pk(fa.x, fa.y); v.y = pk(a2, a3);
        } else if (j == 13) {
            const float* p = p1emb + p1S[li] * POS;
            v.x = pk(p[0], p[1]); v.y = pk(p[2], p[3]);
        } else if (j == 14) {
            const float* p = p2emb + p2S[li] * POS;
            v.x = pk(p[0], p[1]); v.y = pk(p[2], p[3]);
        } else {
            float a = p1emb[p1S[li] * POS + 4];
            float b = p2emb[p2S[li] * POS + 4];
            v.x = pk(a, 0.f); v.y = pk(b, 0.f);
        }
        *(uint2*)(dst + (j < 13 ? j * 4 : 52 + (j - 13) * 4)) = v;
    }
    __syncthreads();

    #pragma unroll 1
    for (int s = 0; s < 2; ++s) {
        const unsigned short* eb = embS + s * SSTR;
        float maxv[2][4];
        #pragma unroll
        for (int t = 0; t < 2; ++t)
            #pragma unroll
            for (int r = 0; r < 4; ++r) maxv[t][r] = -1e30f;

        #pragma unroll
        for (int mt = 0; mt < 8; ++mt) {
            short8 A[KSTEPS];
            #pragma unroll
            for (int ks = 0; ks < KSTEPS; ++ks) {
                int tap = ks >> 1;
                int col = (ks & 1) * 32 + quad * 8;
                int row = mt * 16 + m + tap;
                A[ks] = *(const short8*)(eb + row * ESTR + col);
            }
            f32x4 acc[2];
            #pragma unroll
            for (int t = 0; t < 2; ++t) acc[t] = (f32x4){0.f, 0.f, 0.f, 0.f};
            #pragma unroll
            for (int ks = 0; ks < KSTEPS; ++ks)
                #pragma unroll
                for (int t = 0; t < 2; ++t)
                    acc[t] = __builtin_amdgcn_mfma_f32_16x16x32_bf16(A[ks], Bw[t][ks], acc[t], 0, 0, 0);
            #pragma unroll
            for (int t = 0; t < 2; ++t)
                #pragma unroll
                for (int r = 0; r < 4; ++r)
                    maxv[t][r] = fmaxf(maxv[t][r], acc[t][r]);
        }

        #pragma unroll
        for (int t = 0; t < 2; ++t) {
            float v = fmaxf(fmaxf(maxv[t][0], maxv[t][1]),
                            fmaxf(maxv[t][2], maxv[t][3]));
            v = fmaxf(v, __shfl_xor(v, 16));
            v = fmaxf(v, __shfl_xor(v, 32));
            int c = (nt0 + t) * 16 + lane;
            if (lane < 16 && c < HIDD)
                H[(size_t)(b2 + s) * HSTR + c] = fmaxf(v + conv_b[c], 0.f);
        }
    }
}

// ---- Kernel 3: one wave per bag, zero barriers, all state in registers ----
__global__ __launch_bounds__(64) void attn(
    const float* __restrict__ H, const float* __restrict__ rel_w, const float* __restrict__ rel_b,
    const int* __restrict__ relation, const int* __restrict__ scope,
    float* __restrict__ out)
{
    const int b = blockIdx.x, lane = threadIdx.x;
    const int start = scope[2 * b];
    int ns = scope[2 * b + 1] - start;
    if (ns > 8) ns = 8;
    const int rel = relation[b];

    float q[4], h[8][4];
    #pragma unroll
    for (int k = 0; k < 4; ++k) {
        int c = lane + 64 * k;
        q[k] = (c < HIDD) ? rel_w[rel * HIDD + c] : 0.f;
    }
    #pragma unroll
    for (int s = 0; s < 8; ++s)
        #pragma unroll
        for (int k = 0; k < 4; ++k) {
            int c = lane + 64 * k;
            h[s][k] = (s < ns && c < HIDD) ? H[(size_t)(start + s) * HSTR + c] : 0.f;
        }

    float logit[8];
    #pragma unroll
    for (int s = 0; s < 8; ++s) {
        float t = q[0] * h[s][0] + q[1] * h[s][1] + q[2] * h[s][2] + q[3] * h[s][3];
        #pragma unroll
        for (int off = 32; off > 0; off >>= 1) t += __shfl_xor(t, off);
        logit[s] = t;   // all lanes hold it
    }

    float mx = -1e30f;
    for (int s = 0; s < ns; ++s) mx = fmaxf(mx, logit[s]);
    float a[8], den = 0.f;
    #pragma unroll
    for (int s = 0; s < 8; ++s) { a[s] = (s < ns) ? expf(logit[s] - mx) : 0.f; den += a[s]; }
    float inv = 1.f / den;

    float rep[4];
    #pragma unroll
    for (int k = 0; k < 4; ++k) {
        float r = 0.f;
        #pragma unroll
        for (int s = 0; s < 8; ++s) r += a[s] * h[s][k];
        rep[k] = r * inv;
    }

    // classifier: 25 rows of rel_w, coalesced wave reads (L2-broadcast)
    #pragma unroll 5
    for (int g = 0; g < NREL; ++g) {
        float t = 0.f;
        #pragma unroll
        for (int k = 0; k < 4; ++k) {
            int c = lane + 64 * k;
            t += (c < HIDD) ? rel_w[g * HIDD + c] * rep[k] : 0.f;
        }
        #pragma unroll
        for (int off = 32; off > 0; off >>= 1) t += __shfl_xor(t, off);
        if (lane == 0) out[b * NREL + g] = t + rel_b[g];
    }
}

extern "C" void kernel_launch(void* const* d_in, const int* in_sizes, int n_in,
                              void* d_out, int out_size, void* d_ws, size_t ws_size,
                              hipStream_t stream) {
    const int*   X        = (const int*)d_in[0];
    const int*   P1       = (const int*)d_in[1];
    const int*   P2       = (const int*)d_in[2];
    const int*   scope    = (const int*)d_in[5];
    const int*   relation = (const int*)d_in[6];
    const float* wemb     = (const float*)d_in[7];
    const float* p1emb    = (const float*)d_in[8];
    const float* p2emb    = (const float*)d_in[9];
    const float* conv_w   = (const float*)d_in[10];
    const float* conv_b   = (const float*)d_in[11];
    const float* rel_w    = (const float*)d_in[12];
    const float* rel_b    = (const float*)d_in[13];

    // workspace layout
    char* ws = (char*)d_ws;
    float* H = (float*)ws;                                   // 4000*232*4 = 3,712,000
    const size_t offB = (size_t)NSENT * HSTR * 4;
    unsigned short* Bfrag = (unsigned short*)(ws + offB);    // 16*6*64*8*2 = 98,304
    const size_t offW = offB + (size_t)NTILEP * KSTEPS * 64 * 8 * 2;
    unsigned short* wbf = (unsigned short*)(ws + offW);      // 50002*52*2 = 5,200,208
    const size_t need = offW + (size_t)NVOCAB * WSTR * 2;

    if (ws_size >= need) {
        // merged prep: wbf cvt (2540 blocks) + Bfrag build (192 blocks)
        hipLaunchKernelGGL(prep, dim3(WBLOCKS + 192), dim3(256), 0, stream,
                           conv_w, wemb, Bfrag, wbf);
        hipLaunchKernelGGL(encoder, dim3(NSENT / 2), dim3(512), 0, stream,
                           X, P1, P2, wbf, p1emb, p2emb, Bfrag, conv_b, H);
    } else {
        const int btot = NTILEP * KSTEPS * 64 * 8;
        hipLaunchKernelGGL(prep_b, dim3((btot + 255) / 256), dim3(256), 0, stream,
                           conv_w, Bfrag);
        hipLaunchKernelGGL(encoder_f32, dim3(NSENT / 2), dim3(512), 0, stream,
                           X, P1, P2, wemb, p1emb, p2emb, Bfrag, conv_b, H);
    }
    hipLaunchKernelGGL(attn, dim3(NBAG), dim3(64), 0, stream,
                       H, rel_w, rel_b, relation, scope, (float*)d_out);
}

// Round 8
// 157.591 us; speedup vs baseline: 1.1641x; 1.1421x over previous
//
#include <hip/hip_runtime.h>
#include <hip/hip_bf16.h>

#define NSENT 4000
#define LSEQ  128
#define VEC   50
#define WSTR  52      // bf16 word-emb row stride (shorts): 50 real + 2 zero, 104 B (8B-aligned)
#define NVOCAB 50002
#define POS   5
#define EMBD  60      // VEC + 2*POS
#define HIDD  230
#define HSTR  232     // padded channel stride for H / hS
#define NBAG  500
#define NREL  25
#define BAGSZ 8
#define NTILEP 16     // padded N-tile count (15 real, tile 15 = zeros)
#define KSTEPS 6      // K = 192 (3 taps * 64 e-slots), 6 MFMA K-steps of 32
#define ESTR  72      // LDS row stride in bf16 shorts (144 B)
#define SLOTS 130     // l+1 shift; rows 0/129 are SAME-pad zeros
#define SSTR  (SLOTS * ESTR)   // per-sentence LDS slab (shorts)
#define WBLOCKS 2540  // prep: wbf part = NVOCAB*13 uint2-threads / 256

// e-slot mapping (A and B MUST agree):
//   e 0..49  = wemb dims 0..49      (e50,51 = 0)
//   e 52..55 = p1 dims 0..3
//   e 56..59 = p2 dims 0..3
//   e 60     = p1 dim 4, e61 = 0
//   e 62     = p2 dim 4, e63 = 0
typedef __attribute__((ext_vector_type(8))) short short8;   // 8 bf16 = 4 VGPRs
typedef __attribute__((ext_vector_type(4))) float f32x4;

__device__ __forceinline__ unsigned short f2bf(float f) {
    union { float f; unsigned u; } v; v.f = f;
    unsigned u = v.u + 0x7FFF + ((v.u >> 16) & 1);   // RNE
    return (unsigned short)(u >> 16);
}

// packed f32x2 -> bf16x2 (v_cvt_pk_bf16_f32 on gfx950), low short = first arg
__device__ __forceinline__ unsigned pk(float a, float b) {
    __hip_bfloat162 h = __float22bfloat162_rn(float2{a, b});
    union { __hip_bfloat162 h; unsigned u; } c; c.h = h;
    return c.u;
}

// ---- merged prep: wbf table cvt (blocks < WBLOCKS) + Bfrag build (rest) ----
__global__ __launch_bounds__(256) void prep(const float* __restrict__ conv_w,
                                            const float* __restrict__ wemb,
                                            unsigned short* __restrict__ Bfrag,
                                            unsigned short* __restrict__ wbf) {
    int bid = blockIdx.x;
    if (bid < WBLOCKS) {
        int idx = bid * 256 + threadIdx.x;        // one uint2 (4 shorts) of wbf
        if (idx < NVOCAB * 13) {
            int r = idx / 13, cj = (idx % 13) * 4;
            const float* src = wemb + (size_t)r * VEC + cj;
            float2 a = *(const float2*)src;
            float2 b = (cj < 48) ? *(const float2*)(src + 2) : float2{0.f, 0.f};
            uint2 v; v.x = pk(a.x, a.y); v.y = pk(b.x, b.y);
            *(uint2*)(wbf + (size_t)r * WSTR + cj) = v;
        }
    } else {
        int idx = (bid - WBLOCKS) * 256 + threadIdx.x;
        if (idx >= NTILEP * KSTEPS * 64 * 8) return;
        int j    = idx & 7;
        int lane = (idx >> 3) & 63;
        int t    = idx >> 9;
        int ks   = t % KSTEPS;
        int nt   = t / KSTEPS;
        int c    = nt * 16 + (lane & 15);
        int klin = ks * 32 + (lane >> 4) * 8 + j;
        int tap  = klin >> 6;
        int e    = klin & 63;
        float v  = 0.f;
        if (c < HIDD) {
            int eidx = -1;
            if (e < 50)                 eidx = e;             // wemb dims
            else if (e >= 52 && e < 56) eidx = 50 + (e - 52); // p1[0..3]
            else if (e >= 56 && e < 60) eidx = 55 + (e - 56); // p2[0..3]
            else if (e == 60)           eidx = 54;            // p1[4]
            else if (e == 62)           eidx = 59;            // p2[4]
            if (eidx >= 0) v = conv_w[(c * EMBD + eidx) * 3 + tap];
        }
        Bfrag[idx] = f2bf(v);
    }
}

// ---- standalone prep_b for the fallback path (no wbf region in ws) ----
__global__ __launch_bounds__(256) void prep_b(const float* __restrict__ conv_w,
                                              unsigned short* __restrict__ Bfrag) {
    int idx = blockIdx.x * 256 + threadIdx.x;
    if (idx >= NTILEP * KSTEPS * 64 * 8) return;
    int j    = idx & 7;
    int lane = (idx >> 3) & 63;
    int t    = idx >> 9;
    int ks   = t % KSTEPS;
    int nt   = t / KSTEPS;
    int c    = nt * 16 + (lane & 15);
    int klin = ks * 32 + (lane >> 4) * 8 + j;
    int tap  = klin >> 6;
    int e    = klin & 63;
    float v  = 0.f;
    if (c < HIDD) {
        int eidx = -1;
        if (e < 50)                 eidx = e;
        else if (e >= 52 && e < 56) eidx = 50 + (e - 52);
        else if (e >= 56 && e < 60) eidx = 55 + (e - 56);
        else if (e == 60)           eidx = 54;
        else if (e == 62)           eidx = 59;
        if (eidx >= 0) v = conv_w[(c * EMBD + eidx) * 3 + tap];
    }
    Bfrag[idx] = f2bf(v);
}

// ---- gather one sentence (idx s of the block) into slab; R7-proven code ----
__device__ __forceinline__ void gather_one(
    unsigned short* __restrict__ slab, int s, int tid,
    const int* __restrict__ xS, const int* __restrict__ p1S, const int* __restrict__ p2S,
    const unsigned short* __restrict__ wbf,
    const float* __restrict__ p1emb, const float* __restrict__ p2emb)
{
    #pragma unroll
    for (int it = 0; it < (LSEQ * 16) / 512; ++it) {
        int i = tid + it * 512;
        int l = i >> 4, j = i & 15;
        int li = s * LSEQ + l;
        unsigned short* dst = slab + (l + 1) * ESTR;
        uint2 v;
        if (j < 13) {                 // shorts 4j..4j+3 of bf16 row (j=12 brings the 2 zeros)
            v = *(const uint2*)(wbf + (size_t)xS[li] * WSTR + j * 4);
        } else if (j == 13) {         // p1[0..3] -> e52..55
            const float* p = p1emb + p1S[li] * POS;
            v.x = pk(p[0], p[1]); v.y = pk(p[2], p[3]);
        } else if (j == 14) {         // p2[0..3] -> e56..59
            const float* p = p2emb + p2S[li] * POS;
            v.x = pk(p[0], p[1]); v.y = pk(p[2], p[3]);
        } else {                      // tails -> e60..63
            float a = p1emb[p1S[li] * POS + 4];
            float b = p2emb[p2S[li] * POS + 4];
            v.x = pk(a, 0.f); v.y = pk(b, 0.f);
        }
        *(uint2*)(dst + (j < 13 ? j * 4 : 52 + (j - 13) * 4)) = v;
    }
}

// ---- compute one sentence: PROVEN R5/R7 inner loop; output -> LDS hrow ----
__device__ __forceinline__ void compute_one_lds(
    const unsigned short* __restrict__ eb, const short8 Bw[2][KSTEPS],
    int m, int quad, int nt0, int lane,
    const float* __restrict__ conv_b, float* __restrict__ hrow)
{
    float maxv[2][4];
    #pragma unroll
    for (int t = 0; t < 2; ++t)
        #pragma unroll
        for (int r = 0; r < 4; ++r) maxv[t][r] = -1e30f;

    #pragma unroll
    for (int mt = 0; mt < 8; ++mt) {
        short8 A[KSTEPS];
        #pragma unroll
        for (int ks = 0; ks < KSTEPS; ++ks) {
            int tap = ks >> 1;
            int col = (ks & 1) * 32 + quad * 8;
            int row = mt * 16 + m + tap;        // slot (l+tap), +1 shift folded in
            A[ks] = *(const short8*)(eb + row * ESTR + col);
        }
        f32x4 acc[2];
        #pragma unroll
        for (int t = 0; t < 2; ++t) acc[t] = (f32x4){0.f, 0.f, 0.f, 0.f};
        #pragma unroll
        for (int ks = 0; ks < KSTEPS; ++ks)
            #pragma unroll
            for (int t = 0; t < 2; ++t)
                acc[t] = __builtin_amdgcn_mfma_f32_16x16x32_bf16(A[ks], Bw[t][ks], acc[t], 0, 0, 0);
        #pragma unroll
        for (int t = 0; t < 2; ++t)
            #pragma unroll
            for (int r = 0; r < 4; ++r)
                maxv[t][r] = fmaxf(maxv[t][r], acc[t][r]);
    }

    #pragma unroll
    for (int t = 0; t < 2; ++t) {
        float v = fmaxf(fmaxf(maxv[t][0], maxv[t][1]),
                        fmaxf(maxv[t][2], maxv[t][3]));
        v = fmaxf(v, __shfl_xor(v, 16));
        v = fmaxf(v, __shfl_xor(v, 32));
        int c = (nt0 + t) * 16 + lane;
        if (lane < 16 && c < HIDD)
            hrow[c] = fmaxf(v + conv_b[c], 0.f);
    }
}

// ---- Kernel 2: ONE BLOCK = ONE BAG (8 contiguous sentences) ----
// R7's gather/compute pipeline deepened to 8 sentences through the same two
// LDS slabs (exposed prologue gather: 1 per 8 sentences instead of 1 per 2),
// then the bag attention + classifier run as an LDS tail — the attn kernel,
// its launch gap, and the H global round-trip are deleted. Gather and compute
// bodies are the R7-proven code verbatim; sentence loop is #pragma unroll 1
// with runtime LDS offsets (addresses only — no register-array indexing, no
// liveness growth; R3/R6 proved the allocator rejects >64 VGPR liveness).
// LDS: 37440 (2 slabs) + 12288 (idx) + 7424 (hS) + 960 (lgS/repS) = 58.1 KB.
__global__ __launch_bounds__(512, 4) void encoder_bag(
    const int*   __restrict__ X,  const int* __restrict__ P1, const int* __restrict__ P2,
    const unsigned short* __restrict__ wbf,
    const float* __restrict__ p1emb, const float* __restrict__ p2emb,
    const unsigned short* __restrict__ Bfrag, const float* __restrict__ conv_b,
    const int* __restrict__ relation, const int* __restrict__ scope,
    const float* __restrict__ rel_w, const float* __restrict__ rel_b,
    float* __restrict__ out)
{
    __shared__ unsigned short embS[2 * SSTR];            // 2 alternating slabs
    __shared__ int xS[BAGSZ * LSEQ], p1S[BAGSZ * LSEQ], p2S[BAGSZ * LSEQ];
    __shared__ float hS[BAGSZ][HSTR];                    // encoder outputs
    __shared__ float lgS[BAGSZ];                         // bag logits
    __shared__ float repS[HSTR];                         // bag representation
    const int b = blockIdx.x, tid = threadIdx.x;
    const int lane = tid & 63;
    const int wave = __builtin_amdgcn_readfirstlane(tid >> 6);
    const int nt0  = wave * 2;
    const int m    = lane & 15;
    const int quad = lane >> 4;

    // ---- this wave's B fragments -> registers (48 VGPRs), issued first
    short8 Bw[2][KSTEPS];
    #pragma unroll
    for (int t = 0; t < 2; ++t)
        #pragma unroll
        for (int ks = 0; ks < KSTEPS; ++ks)
            Bw[t][ks] = *(const short8*)(Bfrag + ((size_t)((nt0 + t) * KSTEPS + ks) * 64 + lane) * 8);

    // ---- stage index rows for all 8 sentences (3072 coalesced ints)
    #pragma unroll
    for (int it = 0; it < 6; ++it) {
        int i = tid + it * 512;
        int arr = i >> 10, off = i & 1023;
        const int* src = (arr == 0) ? X : (arr == 1) ? P1 : P2;
        int v = src[(size_t)b * (BAGSZ * LSEQ) + off];
        int* dst = (arr == 0) ? xS : (arr == 1) ? p1S : p2S;
        dst[off] = v;
    }
    // ---- zero SAME-pad rows of both slabs (e-slots 0..63)
    if (tid < 128) {
        int sb = tid >> 6;
        int r = (tid & 32) ? (SLOTS - 1) : 0;
        *(unsigned*)(embS + sb * SSTR + r * ESTR + (tid & 31) * 2) = 0u;
    }
    __syncthreads();

    // ---- pipeline: gather(0); then per round: gather(s+1) || compute(s)
    gather_one(embS, 0, tid, xS, p1S, p2S, wbf, p1emb, p2emb);
    __syncthreads();

    #pragma unroll 1
    for (int s = 0; s < BAGSZ; ++s) {
        if (s < BAGSZ - 1)
            gather_one(embS + ((s + 1) & 1) * SSTR, s + 1, tid, xS, p1S, p2S,
                       wbf, p1emb, p2emb);
        compute_one_lds(embS + (s & 1) * SSTR, Bw, m, quad, nt0, lane,
                        conv_b, &hS[s][0]);
        __syncthreads();
    }

    // ---- bag attention (wave s computes logit of sentence s)
    const int start = scope[2 * b];
    int ns = scope[2 * b + 1] - start;
    if (ns > BAGSZ) ns = BAGSZ;
    const int rel = relation[b];
    {
        float t = 0.f;
        #pragma unroll
        for (int k = 0; k < 4; ++k) {
            int c = lane + 64 * k;
            t += (c < HIDD) ? hS[wave][c] * rel_w[rel * HIDD + c] : 0.f;
        }
        #pragma unroll
        for (int off = 32; off > 0; off >>= 1) t += __shfl_xor(t, off);
        if (lane == 0) lgS[wave] = t;
    }
    __syncthreads();

    float mx = -1e30f;
    #pragma unroll
    for (int s = 0; s < BAGSZ; ++s) if (s < ns) mx = fmaxf(mx, lgS[s]);
    float aw[BAGSZ]; float den = 0.f;
    #pragma unroll
    for (int s = 0; s < BAGSZ; ++s) { aw[s] = (s < ns) ? expf(lgS[s] - mx) : 0.f; den += aw[s]; }
    float inv = 1.f / den;
    if (tid < HIDD) {
        float r = 0.f;
        #pragma unroll
        for (int s = 0; s < BAGSZ; ++s) r += aw[s] * hS[s][tid];
        repS[tid] = r * inv;
    }
    __syncthreads();

    // ---- classifier: wave w handles relations w, w+8, w+16, w+24
    #pragma unroll 1
    for (int g = wave; g < NREL; g += 8) {
        float t = 0.f;
        #pragma unroll
        for (int k = 0; k < 4; ++k) {
            int c = lane + 64 * k;
            t += (c < HIDD) ? repS[c] * rel_w[g * HIDD + c] : 0.f;
        }
        #pragma unroll
        for (int off = 32; off > 0; off >>= 1) t += __shfl_xor(t, off);
        if (lane == 0) out[b * NREL + g] = t + rel_b[g];
    }
}

// ---- fallback: the proven round-0 fused encoder with f32 wemb (verbatim) ----
__global__ __launch_bounds__(512, 4) void encoder_f32(
    const int*   __restrict__ X,  const int* __restrict__ P1, const int* __restrict__ P2,
    const float* __restrict__ wemb, const float* __restrict__ p1emb, const float* __restrict__ p2emb,
    const unsigned short* __restrict__ Bfrag, const float* __restrict__ conv_b,
    float* __restrict__ H)
{
    __shared__ unsigned short embS[2 * SSTR];
    __shared__ int xS[2 * LSEQ], p1S[2 * LSEQ], p2S[2 * LSEQ];
    const int b2 = blockIdx.x * 2, tid = threadIdx.x;
    const int lane = tid & 63;
    const int wave = __builtin_amdgcn_readfirstlane(tid >> 6);
    const int nt0  = wave * 2;
    const int m    = lane & 15;
    const int quad = lane >> 4;

    short8 Bw[2][KSTEPS];
    #pragma unroll
    for (int t = 0; t < 2; ++t)
        #pragma unroll
        for (int ks = 0; ks < KSTEPS; ++ks)
            Bw[t][ks] = *(const short8*)(Bfrag + ((size_t)((nt0 + t) * KSTEPS + ks) * 64 + lane) * 8);

    #pragma unroll
    for (int it = 0; it < 2; ++it) {
        int i = tid + it * 512;
        if (i < 768) {
            int which = i >> 8, l2 = i & 255;
            const int* src = (which == 0) ? X : (which == 1) ? P1 : P2;
            int v = src[(size_t)b2 * LSEQ + l2];
            int* dst = (which == 0) ? xS : (which == 1) ? p1S : p2S;
            dst[l2] = v;
        } else {
            int t = i - 768;
            if (t < 128) {
                int sent = t >> 6;
                int r = (t & 32) ? (SLOTS - 1) : 0;
                *(unsigned*)(embS + sent * SSTR + r * ESTR + (t & 31) * 2) = 0u;
            }
        }
    }
    __syncthreads();

    #pragma unroll
    for (int it = 0; it < (2 * LSEQ * 16) / 512; ++it) {
        int i = tid + it * 512;
        int sent = i >> 11, rem = i & 2047;
        int l = rem >> 4, j = rem & 15;
        int li = sent * LSEQ + l;
        unsigned short* dst = embS + sent * SSTR + (l + 1) * ESTR;
        uint2 v;
        if (j < 13) {
            const float* src = wemb + (size_t)xS[li] * VEC + j * 4;
            float2 fa = *(const float2*)(src);
            float a2 = 0.f, a3 = 0.f;
            if (j < 12) { float2 fb = *(const float2*)(src + 2); a2 = fb.x; a3 = fb.y; }
            v.x = pk(fa.x, fa.y); v.y = pk(a2, a3);
        } else if (j == 13) {
            const float* p = p1emb + p1S[li] * POS;
            v.x = pk(p[0], p[1]); v.y = pk(p[2], p[3]);
        } else if (j == 14) {
            const float* p = p2emb + p2S[li] * POS;
            v.x = pk(p[0], p[1]); v.y = pk(p[2], p[3]);
        } else {
            float a = p1emb[p1S[li] * POS + 4];
            float b = p2emb[p2S[li] * POS + 4];
            v.x = pk(a, 0.f); v.y = pk(b, 0.f);
        }
        *(uint2*)(dst + (j < 13 ? j * 4 : 52 + (j - 13) * 4)) = v;
    }
    __syncthreads();

    #pragma unroll 1
    for (int s = 0; s < 2; ++s) {
        const unsigned short* eb = embS + s * SSTR;
        float maxv[2][4];
        #pragma unroll
        for (int t = 0; t < 2; ++t)
            #pragma unroll
            for (int r = 0; r < 4; ++r) maxv[t][r] = -1e30f;

        #pragma unroll
        for (int mt = 0; mt < 8; ++mt) {
            short8 A[KSTEPS];
            #pragma unroll
            for (int ks = 0; ks < KSTEPS; ++ks) {
                int tap = ks >> 1;
                int col = (ks & 1) * 32 + quad * 8;
                int row = mt * 16 + m + tap;
                A[ks] = *(const short8*)(eb + row * ESTR + col);
            }
            f32x4 acc[2];
            #pragma unroll
            for (int t = 0; t < 2; ++t) acc[t] = (f32x4){0.f, 0.f, 0.f, 0.f};
            #pragma unroll
            for (int ks = 0; ks < KSTEPS; ++ks)
                #pragma unroll
                for (int t = 0; t < 2; ++t)
                    acc[t] = __builtin_amdgcn_mfma_f32_16x16x32_bf16(A[ks], Bw[t][ks], acc[t], 0, 0, 0);
            #pragma unroll
            for (int t = 0; t < 2; ++t)
                #pragma unroll
                for (int r = 0; r < 4; ++r)
                    maxv[t][r] = fmaxf(maxv[t][r], acc[t][r]);
        }

        #pragma unroll
        for (int t = 0; t < 2; ++t) {
            float v = fmaxf(fmaxf(maxv[t][0], maxv[t][1]),
                            fmaxf(maxv[t][2], maxv[t][3]));
            v = fmaxf(v, __shfl_xor(v, 16));
            v = fmaxf(v, __shfl_xor(v, 32));
            int c = (nt0 + t) * 16 + lane;
            if (lane < 16 && c < HIDD)
                H[(size_t)(b2 + s) * HSTR + c] = fmaxf(v + conv_b[c], 0.f);
        }
    }
}

// ---- fallback attn: one wave per bag (verbatim) ----
__global__ __launch_bounds__(64) void attn(
    const float* __restrict__ H, const float* __restrict__ rel_w, const float* __restrict__ rel_b,
    const int* __restrict__ relation, const int* __restrict__ scope,
    float* __restrict__ out)
{
    const int b = blockIdx.x, lane = threadIdx.x;
    const int start = scope[2 * b];
    int ns = scope[2 * b + 1] - start;
    if (ns > 8) ns = 8;
    const int rel = relation[b];

    float q[4], h[8][4];
    #pragma unroll
    for (int k = 0; k < 4; ++k) {
        int c = lane + 64 * k;
        q[k] = (c < HIDD) ? rel_w[rel * HIDD + c] : 0.f;
    }
    #pragma unroll
    for (int s = 0; s < 8; ++s)
        #pragma unroll
        for (int k = 0; k < 4; ++k) {
            int c = lane + 64 * k;
            h[s][k] = (s < ns && c < HIDD) ? H[(size_t)(start + s) * HSTR + c] : 0.f;
        }

    float logit[8];
    #pragma unroll
    for (int s = 0; s < 8; ++s) {
        float t = q[0] * h[s][0] + q[1] * h[s][1] + q[2] * h[s][2] + q[3] * h[s][3];
        #pragma unroll
        for (int off = 32; off > 0; off >>= 1) t += __shfl_xor(t, off);
        logit[s] = t;
    }

    float mx = -1e30f;
    for (int s = 0; s < ns; ++s) mx = fmaxf(mx, logit[s]);
    float a[8], den = 0.f;
    #pragma unroll
    for (int s = 0; s < 8; ++s) { a[s] = (s < ns) ? expf(logit[s] - mx) : 0.f; den += a[s]; }
    float inv = 1.f / den;

    float rep[4];
    #pragma unroll
    for (int k = 0; k < 4; ++k) {
        float r = 0.f;
        #pragma unroll
        for (int s = 0; s < 8; ++s) r += a[s] * h[s][k];
        rep[k] = r * inv;
    }

    #pragma unroll 5
    for (int g = 0; g < NREL; ++g) {
        float t = 0.f;
        #pragma unroll
        for (int k = 0; k < 4; ++k) {
            int c = lane + 64 * k;
            t += (c < HIDD) ? rel_w[g * HIDD + c] * rep[k] : 0.f;
        }
        #pragma unroll
        for (int off = 32; off > 0; off >>= 1) t += __shfl_xor(t, off);
        if (lane == 0) out[b * NREL + g] = t + rel_b[g];
    }
}

extern "C" void kernel_launch(void* const* d_in, const int* in_sizes, int n_in,
                              void* d_out, int out_size, void* d_ws, size_t ws_size,
                              hipStream_t stream) {
    const int*   X        = (const int*)d_in[0];
    const int*   P1       = (const int*)d_in[1];
    const int*   P2       = (const int*)d_in[2];
    const int*   scope    = (const int*)d_in[5];
    const int*   relation = (const int*)d_in[6];
    const float* wemb     = (const float*)d_in[7];
    const float* p1emb    = (const float*)d_in[8];
    const float* p2emb    = (const float*)d_in[9];
    const float* conv_w   = (const float*)d_in[10];
    const float* conv_b   = (const float*)d_in[11];
    const float* rel_w    = (const float*)d_in[12];
    const float* rel_b    = (const float*)d_in[13];

    // workspace layout
    char* ws = (char*)d_ws;
    float* H = (float*)ws;                                   // 4000*232*4 (fallback only)
    const size_t offB = (size_t)NSENT * HSTR * 4;
    unsigned short* Bfrag = (unsigned short*)(ws + offB);    // 16*6*64*8*2 = 98,304
    const size_t offW = offB + (size_t)NTILEP * KSTEPS * 64 * 8 * 2;
    unsigned short* wbf = (unsigned short*)(ws + offW);      // 50002*52*2 = 5,200,208
    const size_t need = offW + (size_t)NVOCAB * WSTR * 2;

    if (ws_size >= need) {
        // merged prep: wbf cvt (2540 blocks) + Bfrag build (192 blocks)
        hipLaunchKernelGGL(prep, dim3(WBLOCKS + 192), dim3(256), 0, stream,
                           conv_w, wemb, Bfrag, wbf);
        // one block = one bag: encoder pipeline + fused attention/classifier
        hipLaunchKernelGGL(encoder_bag, dim3(NBAG), dim3(512), 0, stream,
                           X, P1, P2, wbf, p1emb, p2emb, Bfrag, conv_b,
                           relation, scope, rel_w, rel_b, (float*)d_out);
    } else {
        const int btot = NTILEP * KSTEPS * 64 * 8;
        hipLaunchKernelGGL(prep_b, dim3((btot + 255) / 256), dim3(256), 0, stream,
                           conv_w, Bfrag);
        hipLaunchKernelGGL(encoder_f32, dim3(NSENT / 2), dim3(512), 0, stream,
                           X, P1, P2, wemb, p1emb, p2emb, Bfrag, conv_b, H);
        hipLaunchKernelGGL(attn, dim3(NBAG), dim3(64), 0, stream,
                           H, rel_w, rel_b, relation, scope, (float*)d_out);
    }
}

// Round 9
// 149.236 us; speedup vs baseline: 1.2293x; 1.0560x over previous
//
#include <hip/hip_runtime.h>
#include <hip/hip_bf16.h>

#define NSENT 4000
#define LSEQ  128
#define VEC   50
#define WSTR  52      // bf16 word-emb row stride (shorts): 50 real + 2 zero, 104 B (8B-aligned)
#define NVOCAB 50002
#define POS   5
#define EMBD  60      // VEC + 2*POS
#define HIDD  230
#define HSTR  232     // padded channel stride for H / hS
#define NBAG  500
#define NREL  25
#define BAGSZ 8
#define NTILEP 16     // padded N-tile count (15 real, tile 15 = zeros)
#define KSTEPS 6      // K = 192 (3 taps * 64 e-slots), 6 MFMA K-steps of 32
#define ESTR  72      // LDS row stride in bf16 shorts (144 B)
#define SLOTS 130     // l+1 shift; rows 0/129 are SAME-pad zeros
#define SSTR  (SLOTS * ESTR)   // per-sentence LDS slab (shorts)
#define WBLOCKS 2540  // prep: wbf part = NVOCAB*13 uint2-threads / 256

// e-slot mapping (A and B MUST agree):
//   e 0..49  = wemb dims 0..49      (e50,51 = 0)
//   e 52..55 = p1 dims 0..3
//   e 56..59 = p2 dims 0..3
//   e 60     = p1 dim 4, e61 = 0
//   e 62     = p2 dim 4, e63 = 0
typedef __attribute__((ext_vector_type(8))) short short8;   // 8 bf16 = 4 VGPRs
typedef __attribute__((ext_vector_type(4))) float f32x4;

__device__ __forceinline__ unsigned short f2bf(float f) {
    union { float f; unsigned u; } v; v.f = f;
    unsigned u = v.u + 0x7FFF + ((v.u >> 16) & 1);   // RNE
    return (unsigned short)(u >> 16);
}

// packed f32x2 -> bf16x2 (v_cvt_pk_bf16_f32 on gfx950), low short = first arg
__device__ __forceinline__ unsigned pk(float a, float b) {
    __hip_bfloat162 h = __float22bfloat162_rn(float2{a, b});
    union { __hip_bfloat162 h; unsigned u; } c; c.h = h;
    return c.u;
}

// ---- merged prep: wbf table cvt (blocks < WBLOCKS) + Bfrag build (rest) ----
__global__ __launch_bounds__(256) void prep(const float* __restrict__ conv_w,
                                            const float* __restrict__ wemb,
                                            unsigned short* __restrict__ Bfrag,
                                            unsigned short* __restrict__ wbf) {
    int bid = blockIdx.x;
    if (bid < WBLOCKS) {
        int idx = bid * 256 + threadIdx.x;        // one uint2 (4 shorts) of wbf
        if (idx < NVOCAB * 13) {
            int r = idx / 13, cj = (idx % 13) * 4;
            const float* src = wemb + (size_t)r * VEC + cj;
            float2 a = *(const float2*)src;
            float2 b = (cj < 48) ? *(const float2*)(src + 2) : float2{0.f, 0.f};
            uint2 v; v.x = pk(a.x, a.y); v.y = pk(b.x, b.y);
            *(uint2*)(wbf + (size_t)r * WSTR + cj) = v;
        }
    } else {
        int idx = (bid - WBLOCKS) * 256 + threadIdx.x;
        if (idx >= NTILEP * KSTEPS * 64 * 8) return;
        int j    = idx & 7;
        int lane = (idx >> 3) & 63;
        int t    = idx >> 9;
        int ks   = t % KSTEPS;
        int nt   = t / KSTEPS;
        int c    = nt * 16 + (lane & 15);
        int klin = ks * 32 + (lane >> 4) * 8 + j;
        int tap  = klin >> 6;
        int e    = klin & 63;
        float v  = 0.f;
        if (c < HIDD) {
            int eidx = -1;
            if (e < 50)                 eidx = e;             // wemb dims
            else if (e >= 52 && e < 56) eidx = 50 + (e - 52); // p1[0..3]
            else if (e >= 56 && e < 60) eidx = 55 + (e - 56); // p2[0..3]
            else if (e == 60)           eidx = 54;            // p1[4]
            else if (e == 62)           eidx = 59;            // p2[4]
            if (eidx >= 0) v = conv_w[(c * EMBD + eidx) * 3 + tap];
        }
        Bfrag[idx] = f2bf(v);
    }
}

// ---- standalone prep_b for the fallback path (no wbf region in ws) ----
__global__ __launch_bounds__(256) void prep_b(const float* __restrict__ conv_w,
                                              unsigned short* __restrict__ Bfrag) {
    int idx = blockIdx.x * 256 + threadIdx.x;
    if (idx >= NTILEP * KSTEPS * 64 * 8) return;
    int j    = idx & 7;
    int lane = (idx >> 3) & 63;
    int t    = idx >> 9;
    int ks   = t % KSTEPS;
    int nt   = t / KSTEPS;
    int c    = nt * 16 + (lane & 15);
    int klin = ks * 32 + (lane >> 4) * 8 + j;
    int tap  = klin >> 6;
    int e    = klin & 63;
    float v  = 0.f;
    if (c < HIDD) {
        int eidx = -1;
        if (e < 50)                 eidx = e;
        else if (e >= 52 && e < 56) eidx = 50 + (e - 52);
        else if (e >= 56 && e < 60) eidx = 55 + (e - 56);
        else if (e == 60)           eidx = 54;
        else if (e == 62)           eidx = 59;
        if (eidx >= 0) v = conv_w[(c * EMBD + eidx) * 3 + tap];
    }
    Bfrag[idx] = f2bf(v);
}

// ---- gather one sentence (prologue only); R7-proven code ----
__device__ __forceinline__ void gather_one(
    unsigned short* __restrict__ slab, int s, int tid,
    const int* __restrict__ xS, const int* __restrict__ p1S, const int* __restrict__ p2S,
    const unsigned short* __restrict__ wbf,
    const float* __restrict__ p1emb, const float* __restrict__ p2emb)
{
    #pragma unroll
    for (int it = 0; it < (LSEQ * 16) / 512; ++it) {
        int i = tid + it * 512;
        int l = i >> 4, j = i & 15;
        int li = s * LSEQ + l;
        unsigned short* dst = slab + (l + 1) * ESTR;
        uint2 v;
        if (j < 13) {                 // shorts 4j..4j+3 of bf16 row (j=12 brings the 2 zeros)
            v = *(const uint2*)(wbf + (size_t)xS[li] * WSTR + j * 4);
        } else if (j == 13) {         // p1[0..3] -> e52..55
            const float* p = p1emb + p1S[li] * POS;
            v.x = pk(p[0], p[1]); v.y = pk(p[2], p[3]);
        } else if (j == 14) {         // p2[0..3] -> e56..59
            const float* p = p2emb + p2S[li] * POS;
            v.x = pk(p[0], p[1]); v.y = pk(p[2], p[3]);
        } else {                      // tails -> e60..63
            float a = p1emb[p1S[li] * POS + 4];
            float b = p2emb[p2S[li] * POS + 4];
            v.x = pk(a, 0.f); v.y = pk(b, 0.f);
        }
        *(uint2*)(dst + (j < 13 ? j * 4 : 52 + (j - 13) * 4)) = v;
    }
}

// ---- compute one sentence: PROVEN R5/R7 inner loop; output -> LDS hrow ----
__device__ __forceinline__ void compute_one_lds(
    const unsigned short* __restrict__ eb, const short8 Bw[2][KSTEPS],
    int m, int quad, int nt0, int lane,
    const float* __restrict__ conv_b, float* __restrict__ hrow)
{
    float maxv[2][4];
    #pragma unroll
    for (int t = 0; t < 2; ++t)
        #pragma unroll
        for (int r = 0; r < 4; ++r) maxv[t][r] = -1e30f;

    #pragma unroll
    for (int mt = 0; mt < 8; ++mt) {
        short8 A[KSTEPS];
        #pragma unroll
        for (int ks = 0; ks < KSTEPS; ++ks) {
            int tap = ks >> 1;
            int col = (ks & 1) * 32 + quad * 8;
            int row = mt * 16 + m + tap;        // slot (l+tap), +1 shift folded in
            A[ks] = *(const short8*)(eb + row * ESTR + col);
        }
        f32x4 acc[2];
        #pragma unroll
        for (int t = 0; t < 2; ++t) acc[t] = (f32x4){0.f, 0.f, 0.f, 0.f};
        #pragma unroll
        for (int ks = 0; ks < KSTEPS; ++ks)
            #pragma unroll
            for (int t = 0; t < 2; ++t)
                acc[t] = __builtin_amdgcn_mfma_f32_16x16x32_bf16(A[ks], Bw[t][ks], acc[t], 0, 0, 0);
        #pragma unroll
        for (int t = 0; t < 2; ++t)
            #pragma unroll
            for (int r = 0; r < 4; ++r)
                maxv[t][r] = fmaxf(maxv[t][r], acc[t][r]);
    }

    #pragma unroll
    for (int t = 0; t < 2; ++t) {
        float v = fmaxf(fmaxf(maxv[t][0], maxv[t][1]),
                        fmaxf(maxv[t][2], maxv[t][3]));
        v = fmaxf(v, __shfl_xor(v, 16));
        v = fmaxf(v, __shfl_xor(v, 32));
        int c = (nt0 + t) * 16 + lane;
        if (lane < 16 && c < HIDD)
            hrow[c] = fmaxf(v + conv_b[c], 0.f);
    }
}

// ---- Kernel 2: ONE BLOCK = ONE BAG, T14 split-gather pipeline ----
// R8 structure (157.6us total measured) with ONE change: each round's gather
// is split into {phase L: issue loads, hold raw results in 8 VGPRs} ->
// sched_barrier -> compute(s) -> sched_barrier -> {phase W: ds_writes}.
// Key lane fact: j = tid&15 is CONSTANT across a thread's 4 gather iters, so
// 13/16 of lanes hold raw wbf uint2s with NO conversion (vmcnt wait migrates
// to after the MFMA stream); the 3/16 pos lanes load from the tiny L1-resident
// pos tables FIRST (cheap early wait that doesn't drain the wemb loads).
// sched_barrier(0) pins the order so the allocator can't re-serialize
// (R6's failure mode). Liveness: +8 VGPR (vs R6's rejected +52).
// TRIPWIRE: VGPR>96 or WRITE_SIZE spike => spill => revert to R8.
// LDS: 37440 (2 slabs) + 12288 (idx) + 7424 (hS) + 960 (lgS/repS) = 58.1 KB.
__global__ __launch_bounds__(512, 4) void encoder_bag(
    const int*   __restrict__ X,  const int* __restrict__ P1, const int* __restrict__ P2,
    const unsigned short* __restrict__ wbf,
    const float* __restrict__ p1emb, const float* __restrict__ p2emb,
    const unsigned short* __restrict__ Bfrag, const float* __restrict__ conv_b,
    const int* __restrict__ relation, const int* __restrict__ scope,
    const float* __restrict__ rel_w, const float* __restrict__ rel_b,
    float* __restrict__ out)
{
    __shared__ unsigned short embS[2 * SSTR];            // 2 alternating slabs
    __shared__ int xS[BAGSZ * LSEQ], p1S[BAGSZ * LSEQ], p2S[BAGSZ * LSEQ];
    __shared__ float hS[BAGSZ][HSTR];                    // encoder outputs
    __shared__ float lgS[BAGSZ];                         // bag logits
    __shared__ float repS[HSTR];                         // bag representation
    const int b = blockIdx.x, tid = threadIdx.x;
    const int lane = tid & 63;
    const int wave = __builtin_amdgcn_readfirstlane(tid >> 6);
    const int nt0  = wave * 2;
    const int m    = lane & 15;
    const int quad = lane >> 4;
    const int jj   = tid & 15;     // gather column role, constant per thread
    const int l0   = tid >> 4;     // gather base token, +32 per iteration

    // ---- this wave's B fragments -> registers (48 VGPRs), issued first
    short8 Bw[2][KSTEPS];
    #pragma unroll
    for (int t = 0; t < 2; ++t)
        #pragma unroll
        for (int ks = 0; ks < KSTEPS; ++ks)
            Bw[t][ks] = *(const short8*)(Bfrag + ((size_t)((nt0 + t) * KSTEPS + ks) * 64 + lane) * 8);

    // ---- stage index rows for all 8 sentences (3072 coalesced ints)
    #pragma unroll
    for (int it = 0; it < 6; ++it) {
        int i = tid + it * 512;
        int arr = i >> 10, off = i & 1023;
        const int* src = (arr == 0) ? X : (arr == 1) ? P1 : P2;
        int v = src[(size_t)b * (BAGSZ * LSEQ) + off];
        int* dst = (arr == 0) ? xS : (arr == 1) ? p1S : p2S;
        dst[off] = v;
    }
    // ---- zero SAME-pad rows of both slabs (e-slots 0..63)
    if (tid < 128) {
        int sb = tid >> 6;
        int r = (tid & 32) ? (SLOTS - 1) : 0;
        *(unsigned*)(embS + sb * SSTR + r * ESTR + (tid & 31) * 2) = 0u;
    }
    __syncthreads();

    // ---- pipeline: gather(0); then per round: loadL(s+1); compute(s); writeW(s+1)
    gather_one(embS, 0, tid, xS, p1S, p2S, wbf, p1emb, p2emb);
    __syncthreads();

    #pragma unroll 1
    for (int s = 0; s < BAGSZ; ++s) {
        const int sn = s + 1;
        const bool do_g = (sn < BAGSZ);
        uint2 gv[4];                                   // statically indexed (unrolled)

        // ---- phase L: pos lanes first (tiny tables, cheap wait), wemb raw last
        if (do_g) {
            if (jj >= 13) {
                #pragma unroll
                for (int it = 0; it < 4; ++it) {
                    int li = sn * LSEQ + l0 + it * 32;
                    if (jj == 13) {
                        const float* p = p1emb + p1S[li] * POS;
                        gv[it].x = pk(p[0], p[1]); gv[it].y = pk(p[2], p[3]);
                    } else if (jj == 14) {
                        const float* p = p2emb + p2S[li] * POS;
                        gv[it].x = pk(p[0], p[1]); gv[it].y = pk(p[2], p[3]);
                    } else {
                        float a = p1emb[p1S[li] * POS + 4];
                        float c = p2emb[p2S[li] * POS + 4];
                        gv[it].x = pk(a, 0.f); gv[it].y = pk(c, 0.f);
                    }
                }
            } else {
                #pragma unroll
                for (int it = 0; it < 4; ++it) {
                    int li = sn * LSEQ + l0 + it * 32;
                    gv[it] = *(const uint2*)(wbf + (size_t)xS[li] * WSTR + jj * 4);
                }
            }
        }
        __builtin_amdgcn_sched_barrier(0);

        // ---- compute current sentence (vmcnt for wemb loads migrates past this)
        compute_one_lds(embS + (s & 1) * SSTR, Bw, m, quad, nt0, lane,
                        conv_b, &hS[s][0]);
        __builtin_amdgcn_sched_barrier(0);

        // ---- phase W: write held gather results into the other slab
        if (do_g) {
            unsigned short* slab = embS + (sn & 1) * SSTR;
            int off = (jj < 13) ? jj * 4 : 52 + (jj - 13) * 4;
            #pragma unroll
            for (int it = 0; it < 4; ++it) {
                int l = l0 + it * 32;
                *(uint2*)(slab + (l + 1) * ESTR + off) = gv[it];
            }
        }
        __syncthreads();
    }

    // ---- bag attention (wave s computes logit of sentence s)
    const int start = scope[2 * b];
    int ns = scope[2 * b + 1] - start;
    if (ns > BAGSZ) ns = BAGSZ;
    const int rel = relation[b];
    {
        float t = 0.f;
        #pragma unroll
        for (int k = 0; k < 4; ++k) {
            int c = lane + 64 * k;
            t += (c < HIDD) ? hS[wave][c] * rel_w[rel * HIDD + c] : 0.f;
        }
        #pragma unroll
        for (int off = 32; off > 0; off >>= 1) t += __shfl_xor(t, off);
        if (lane == 0) lgS[wave] = t;
    }
    __syncthreads();

    float mx = -1e30f;
    #pragma unroll
    for (int s = 0; s < BAGSZ; ++s) if (s < ns) mx = fmaxf(mx, lgS[s]);
    float aw[BAGSZ]; float den = 0.f;
    #pragma unroll
    for (int s = 0; s < BAGSZ; ++s) { aw[s] = (s < ns) ? expf(lgS[s] - mx) : 0.f; den += aw[s]; }
    float inv = 1.f / den;
    if (tid < HIDD) {
        float r = 0.f;
        #pragma unroll
        for (int s = 0; s < BAGSZ; ++s) r += aw[s] * hS[s][tid];
        repS[tid] = r * inv;
    }
    __syncthreads();

    // ---- classifier: wave w handles relations w, w+8, w+16, w+24
    #pragma unroll 1
    for (int g = wave; g < NREL; g += 8) {
        float t = 0.f;
        #pragma unroll
        for (int k = 0; k < 4; ++k) {
            int c = lane + 64 * k;
            t += (c < HIDD) ? repS[c] * rel_w[g * HIDD + c] : 0.f;
        }
        #pragma unroll
        for (int off = 32; off > 0; off >>= 1) t += __shfl_xor(t, off);
        if (lane == 0) out[b * NREL + g] = t + rel_b[g];
    }
}

// ---- fallback: the proven round-0 fused encoder with f32 wemb (verbatim) ----
__global__ __launch_bounds__(512, 4) void encoder_f32(
    const int*   __restrict__ X,  const int* __restrict__ P1, const int* __restrict__ P2,
    const float* __restrict__ wemb, const float* __restrict__ p1emb, const float* __restrict__ p2emb,
    const unsigned short* __restrict__ Bfrag, const float* __restrict__ conv_b,
    float* __restrict__ H)
{
    __shared__ unsigned short embS[2 * SSTR];
    __shared__ int xS[2 * LSEQ], p1S[2 * LSEQ], p2S[2 * LSEQ];
    const int b2 = blockIdx.x * 2, tid = threadIdx.x;
    const int lane = tid & 63;
    const int wave = __builtin_amdgcn_readfirstlane(tid >> 6);
    const int nt0  = wave * 2;
    const int m    = lane & 15;
    const int quad = lane >> 4;

    short8 Bw[2][KSTEPS];
    #pragma unroll
    for (int t = 0; t < 2; ++t)
        #pragma unroll
        for (int ks = 0; ks < KSTEPS; ++ks)
            Bw[t][ks] = *(const short8*)(Bfrag + ((size_t)((nt0 + t) * KSTEPS + ks) * 64 + lane) * 8);

    #pragma unroll
    for (int it = 0; it < 2; ++it) {
        int i = tid + it * 512;
        if (i < 768) {
            int which = i >> 8, l2 = i & 255;
            const int* src = (which == 0) ? X : (which == 1) ? P1 : P2;
            int v = src[(size_t)b2 * LSEQ + l2];
            int* dst = (which == 0) ? xS : (which == 1) ? p1S : p2S;
            dst[l2] = v;
        } else {
            int t = i - 768;
            if (t < 128) {
                int sent = t >> 6;
                int r = (t & 32) ? (SLOTS - 1) : 0;
                *(unsigned*)(embS + sent * SSTR + r * ESTR + (t & 31) * 2) = 0u;
            }
        }
    }
    __syncthreads();

    #pragma unroll
    for (int it = 0; it < (2 * LSEQ * 16) / 512; ++it) {
        int i = tid + it * 512;
        int sent = i >> 11, rem = i & 2047;
        int l = rem >> 4, j = rem & 15;
        int li = sent * LSEQ + l;
        unsigned short* dst = embS + sent * SSTR + (l + 1) * ESTR;
        uint2 v;
        if (j < 13) {
            const float* src = wemb + (size_t)xS[li] * VEC + j * 4;
            float2 fa = *(const float2*)(src);
            float a2 = 0.f, a3 = 0.f;
            if (j < 12) { float2 fb = *(const float2*)(src + 2); a2 = fb.x; a3 = fb.y; }
            v.x = pk(fa.x, fa.y); v.y = pk(a2, a3);
        } else if (j == 13) {
            const float* p = p1emb + p1S[li] * POS;
            v.x = pk(p[0], p[1]); v.y = pk(p[2], p[3]);
        } else if (j == 14) {
            const float* p = p2emb + p2S[li] * POS;
            v.x = pk(p[0], p[1]); v.y = pk(p[2], p[3]);
        } else {
            float a = p1emb[p1S[li] * POS + 4];
            float b = p2emb[p2S[li] * POS + 4];
            v.x = pk(a, 0.f); v.y = pk(b, 0.f);
        }
        *(uint2*)(dst + (j < 13 ? j * 4 : 52 + (j - 13) * 4)) = v;
    }
    __syncthreads();

    #pragma unroll 1
    for (int s = 0; s < 2; ++s) {
        const unsigned short* eb = embS + s * SSTR;
        float maxv[2][4];
        #pragma unroll
        for (int t = 0; t < 2; ++t)
            #pragma unroll
            for (int r = 0; r < 4; ++r) maxv[t][r] = -1e30f;

        #pragma unroll
        for (int mt = 0; mt < 8; ++mt) {
            short8 A[KSTEPS];
            #pragma unroll
            for (int ks = 0; ks < KSTEPS; ++ks) {
                int tap = ks >> 1;
                int col = (ks & 1) * 32 + quad * 8;
                int row = mt * 16 + m + tap;
                A[ks] = *(const short8*)(eb + row * ESTR + col);
            }
            f32x4 acc[2];
            #pragma unroll
            for (int t = 0; t < 2; ++t) acc[t] = (f32x4){0.f, 0.f, 0.f, 0.f};
            #pragma unroll
            for (int ks = 0; ks < KSTEPS; ++ks)
                #pragma unroll
                for (int t = 0; t < 2; ++t)
                    acc[t] = __builtin_amdgcn_mfma_f32_16x16x32_bf16(A[ks], Bw[t][ks], acc[t], 0, 0, 0);
            #pragma unroll
            for (int t = 0; t < 2; ++t)
                #pragma unroll
                for (int r = 0; r < 4; ++r)
                    maxv[t][r] = fmaxf(maxv[t][r], acc[t][r]);
        }

        #pragma unroll
        for (int t = 0; t < 2; ++t) {
            float v = fmaxf(fmaxf(maxv[t][0], maxv[t][1]),
                            fmaxf(maxv[t][2], maxv[t][3]));
            v = fmaxf(v, __shfl_xor(v, 16));
            v = fmaxf(v, __shfl_xor(v, 32));
            int c = (nt0 + t) * 16 + lane;
            if (lane < 16 && c < HIDD)
                H[(size_t)(b2 + s) * HSTR + c] = fmaxf(v + conv_b[c], 0.f);
        }
    }
}

// ---- fallback attn: one wave per bag (verbatim) ----
__global__ __launch_bounds__(64) void attn(
    const float* __restrict__ H, const float* __restrict__ rel_w, const float* __restrict__ rel_b,
    const int* __restrict__ relation, const int* __restrict__ scope,
    float* __restrict__ out)
{
    const int b = blockIdx.x, lane = threadIdx.x;
    const int start = scope[2 * b];
    int ns = scope[2 * b + 1] - start;
    if (ns > 8) ns = 8;
    const int rel = relation[b];

    float q[4], h[8][4];
    #pragma unroll
    for (int k = 0; k < 4; ++k) {
        int c = lane + 64 * k;
        q[k] = (c < HIDD) ? rel_w[rel * HIDD + c] : 0.f;
    }
    #pragma unroll
    for (int s = 0; s < 8; ++s)
        #pragma unroll
        for (int k = 0; k < 4; ++k) {
            int c = lane + 64 * k;
            h[s][k] = (s < ns && c < HIDD) ? H[(size_t)(start + s) * HSTR + c] : 0.f;
        }

    float logit[8];
    #pragma unroll
    for (int s = 0; s < 8; ++s) {
        float t = q[0] * h[s][0] + q[1] * h[s][1] + q[2] * h[s][2] + q[3] * h[s][3];
        #pragma unroll
        for (int off = 32; off > 0; off >>= 1) t += __shfl_xor(t, off);
        logit[s] = t;
    }

    float mx = -1e30f;
    for (int s = 0; s < ns; ++s) mx = fmaxf(mx, logit[s]);
    float a[8], den = 0.f;
    #pragma unroll
    for (int s = 0; s < 8; ++s) { a[s] = (s < ns) ? expf(logit[s] - mx) : 0.f; den += a[s]; }
    float inv = 1.f / den;

    float rep[4];
    #pragma unroll
    for (int k = 0; k < 4; ++k) {
        float r = 0.f;
        #pragma unroll
        for (int s = 0; s < 8; ++s) r += a[s] * h[s][k];
        rep[k] = r * inv;
    }

    #pragma unroll 5
    for (int g = 0; g < NREL; ++g) {
        float t = 0.f;
        #pragma unroll
        for (int k = 0; k < 4; ++k) {
            int c = lane + 64 * k;
            t += (c < HIDD) ? rel_w[g * HIDD + c] * rep[k] : 0.f;
        }
        #pragma unroll
        for (int off = 32; off > 0; off >>= 1) t += __shfl_xor(t, off);
        if (lane == 0) out[b * NREL + g] = t + rel_b[g];
    }
}

extern "C" void kernel_launch(void* const* d_in, const int* in_sizes, int n_in,
                              void* d_out, int out_size, void* d_ws, size_t ws_size,
                              hipStream_t stream) {
    const int*   X        = (const int*)d_in[0];
    const int*   P1       = (const int*)d_in[1];
    const int*   P2       = (const int*)d_in[2];
    const int*   scope    = (const int*)d_in[5];
    const int*   relation = (const int*)d_in[6];
    const float* wemb     = (const float*)d_in[7];
    const float* p1emb    = (const float*)d_in[8];
    const float* p2emb    = (const float*)d_in[9];
    const float* conv_w   = (const float*)d_in[10];
    const float* conv_b   = (const float*)d_in[11];
    const float* rel_w    = (const float*)d_in[12];
    const float* rel_b    = (const float*)d_in[13];

    // workspace layout
    char* ws = (char*)d_ws;
    float* H = (float*)ws;                                   // 4000*232*4 (fallback only)
    const size_t offB = (size_t)NSENT * HSTR * 4;
    unsigned short* Bfrag = (unsigned short*)(ws + offB);    // 16*6*64*8*2 = 98,304
    const size_t offW = offB + (size_t)NTILEP * KSTEPS * 64 * 8 * 2;
    unsigned short* wbf = (unsigned short*)(ws + offW);      // 50002*52*2 = 5,200,208
    const size_t need = offW + (size_t)NVOCAB * WSTR * 2;

    if (ws_size >= need) {
        // merged prep: wbf cvt (2540 blocks) + Bfrag build (192 blocks)
        hipLaunchKernelGGL(prep, dim3(WBLOCKS + 192), dim3(256), 0, stream,
                           conv_w, wemb, Bfrag, wbf);
        // one block = one bag: encoder pipeline + fused attention/classifier
        hipLaunchKernelGGL(encoder_bag, dim3(NBAG), dim3(512), 0, stream,
                           X, P1, P2, wbf, p1emb, p2emb, Bfrag, conv_b,
                           relation, scope, rel_w, rel_b, (float*)d_out);
    } else {
        const int btot = NTILEP * KSTEPS * 64 * 8;
        hipLaunchKernelGGL(prep_b, dim3((btot + 255) / 256), dim3(256), 0, stream,
                           conv_w, Bfrag);
        hipLaunchKernelGGL(encoder_f32, dim3(NSENT / 2), dim3(512), 0, stream,
                           X, P1, P2, wemb, p1emb, p2emb, Bfrag, conv_b, H);
        hipLaunchKernelGGL(attn, dim3(NBAG), dim3(64), 0, stream,
                           H, rel_w, rel_b, relation, scope, (float*)d_out);
    }
}